// Round 11
// baseline (150.259 us; speedup 1.0000x reference)
//
#include <hip/hip_runtime.h>

// Problem constants
static constexpr int B_ = 64, A_ = 32, BOARD_ = 64, D_ = 5;
static constexpr long long FACN = (long long)B_ * A_ * BOARD_ * BOARD_ * D_; // 41,943,040 floats
static constexpr long long CHN  = (long long)B_ * A_ * BOARD_ * BOARD_;      //  8,388,608 floats
static constexpr int NAG = B_ * A_;                                          // 2048 agents
static constexpr int SL  = BOARD_ * BOARD_ * D_;                             // 20480 floats / agent fac slab
static constexpr int SLC = BOARD_ * BOARD_;                                  //  4096 floats / agent ch slab

// exp(-1/50), exp(-1/20)
static constexpr float FAC_DECAY = 0.9801986733067553f;
static constexpr float INH_DECAY = 0.9512294245007140f;

typedef float f32x4 __attribute__((ext_vector_type(4)));

// Fused kernel, 2048 blocks x 256 threads.
// SINGLE-VARIABLE EXPERIMENT vs r9: streaming stores are PLAIN (cached)
// instead of nontemporal. Rationale: d_out (369 MB) is not re-poisoned
// between graph replays and LLC is 256 MB -> cached stores can stay
// resident-dirty in LLC and be overwritten in place next replay, cutting
// per-replay DRAM write traffic. Loads stay nt (read-once; must not
// allocate LLC and evict the dirty out lines).
//
// Phase 1 (streaming): block b owns contiguous vectors [b*11264, (b+1)*11264)
// of out = [fac | inh | ch]; group starts & region boundaries are multiples of
// 1024 vectors -> wave-uniform region pick; software-pipelined.
// Phase 2 (corrections): after __syncthreads, overwrite the agent-scatter
// cells inside THIS block's float range with values from the ORIGINAL inputs.
// Each out-float has exactly one writer block -> no cross-block race.
__global__ __launch_bounds__(256) void fused_kernel(
    const f32x4* __restrict__ fac4, const f32x4* __restrict__ inh4,
    const f32x4* __restrict__ ch4, f32x4* __restrict__ out4,
    const float* __restrict__ pos, const float* __restrict__ goal,
    const float* __restrict__ spike,
    const float* __restrict__ fac_in, const float* __restrict__ inh_in,
    const float* __restrict__ ch_in,
    const void* __restrict__ coll,
    float* __restrict__ out)
{
    const int FACV = (int)(FACN / 4);       // 10,485,760 vectors (= 10240*1024)
    const int C = 11264;                    // vectors per block (11*1024); 2048*C = total
    const int t = threadIdx.x;
    const int bid = blockIdx.x;
    const int base = bid * C;

    __shared__ int s_w4, s_h2;
    if (t == 0) { s_w4 = 1; s_h2 = 1; }
    __syncthreads();

    // ---- Phase 1: streaming decay ----
    auto ldgrp = [&](int G, f32x4 v[4], float& c) {
        const f32x4* __restrict__ s;
        if (G < FACV)          { s = fac4 + G;             c = FAC_DECAY; }
        else if (G < 2 * FACV) { s = inh4 + (G - FACV);    c = INH_DECAY; }
        else                   { s = ch4 + (G - 2 * FACV); c = 0.9f; }
        v[0] = __builtin_nontemporal_load(&s[t]);
        v[1] = __builtin_nontemporal_load(&s[t + 256]);
        v[2] = __builtin_nontemporal_load(&s[t + 512]);
        v[3] = __builtin_nontemporal_load(&s[t + 768]);
    };

    {
        f32x4 v[4]; float c;
        ldgrp(base, v, c);
        int off = 0;
        while (true) {
            f32x4 w[4]; float c2;
            const int noff = off + 1024;
            if (noff < C) ldgrp(base + noff, w, c2);   // prefetch next group first
            f32x4* __restrict__ d = out4 + base + off;
            d[t]       = v[0] * c;     // PLAIN stores (cached) — the experiment
            d[t + 256] = v[1] * c;
            d[t + 512] = v[2] * c;
            d[t + 768] = v[3] * c;
            if (noff >= C) break;
            v[0] = w[0]; v[1] = w[1]; v[2] = w[2]; v[3] = w[3]; c = c2;
            off = noff;
        }
    }

    // ---- collisions-dtype sniff (2048 bytes = smallest possible encoding) ----
    {
        const unsigned int* cw = (const unsigned int*)coll;
        for (int k = t; k < 512; k += 256) {
            unsigned int w = cw[k];
            if (!(w == 0u || w == 1u || w == 0x3F800000u)) s_w4 = 0;
            unsigned int lo = w & 0xFFFFu, hi = w >> 16;
            if (!((lo == 0u || lo == 1u || lo == 0x3F80u || lo == 0x3C00u) &&
                  (hi == 0u || hi == 1u || hi == 0x3F80u || hi == 0x3C00u)))
                s_h2 = 0;
        }
    }
    __threadfence_block();
    __syncthreads();   // this block's streaming stores ordered; sniff flags ready
    const int f = s_w4 ? 4 : (s_h2 ? 2 : 1);

    // ---- Phase 2: chunk-local agent corrections ----
    const long long CF = 45056;             // floats per chunk (= C*4)
    const long long F0 = (long long)bid * CF, F1 = F0 + CF;

    auto fix_agent = [&](int ia, int region) {  // region 0=fac, 1=inh, 2=ch
        float px = pos[ia * 2 + 0];
        float py = pos[ia * 2 + 1];
        int x = min(BOARD_ - 1, max(0, (int)px));   // trunc like .astype(int32); pos >= 0
        int y = min(BOARD_ - 1, max(0, (int)py));
        int lcell = y * BOARD_ + x;                 // 0..4095

        bool c;
        if (f == 4)      c = ((const unsigned int*)coll)[ia] != 0u;
        else if (f == 2) c = ((const unsigned short*)coll)[ia] != 0u;
        else             c = ((const unsigned char*)coll)[ia] != 0u;

        float chv = ch_in[(long long)ia * SLC + lcell] * 0.9f + (c ? 0.1f : 0.0f);
        float safety = 1.0f - fminf(fmaxf(chv, 0.0f), 1.0f);

        if (region == 2) {
            long long fl = 2 * FACN + (long long)ia * SLC + lcell;
            if (fl >= F0 && fl < F1) out[fl] = chv;
            return;
        }

        bool safe = safety > 0.7f;
        float gx = goal[ia * 2 + 0] - px;
        float gy = goal[ia * 2 + 1] - py;
        float n = sqrtf(gx * gx + gy * gy) + 1e-8f;
        float gnx = gx / n, gny = gy / n;
        float align[5];
        align[0] = 0.5f;
        align[1] = (gnx + 1.0f) * 0.5f;
        align[2] = (gny + 1.0f) * 0.5f;
        align[3] = (1.0f - gnx) * 0.5f;
        align[4] = (1.0f - gny) * 0.5f;

        long long cdb = (long long)ia * SL + (long long)lcell * D_;  // within-region float base
#pragma unroll
        for (int d = 0; d < D_; ++d) {
            bool sp = spike[ia * D_ + d] > 0.5f;
            long long fl;
            float v;
            if (region == 0) {
                bool fc = sp && safe && (align[d] > 0.6f);
                v = fac_in[cdb + d] * FAC_DECAY + (fc ? 0.0002f : 0.0f);
                fl = cdb + d;
            } else {
                bool ic = sp && (!safe || (align[d] <= 0.4f));
                v = inh_in[cdb + d] * INH_DECAY + (ic ? 0.0001f : 0.0f);
                fl = FACN + cdb + d;
            }
            if (fl >= F0 && fl < F1) out[fl] = v;
        }
    };

    // fac region intersection: [F0, F1) ∩ [0, FACN)
    if (t < 4) {
        long long a1 = min(F1, FACN);
        if (F0 < a1) {
            int ia = (int)(F0 / SL) + t;
            int iaMax = (int)((a1 - 1) / SL);
            if (ia <= iaMax && ia < NAG) fix_agent(ia, 0);
        }
    }
    // inh region intersection: [F0, F1) ∩ [FACN, 2*FACN)
    else if (t >= 8 && t < 12) {
        long long b0 = max(F0, FACN), b1 = min(F1, 2 * FACN);
        if (b0 < b1) {
            int ia = (int)((b0 - FACN) / SL) + (t - 8);
            int iaMax = (int)((b1 - FACN - 1) / SL);
            if (ia <= iaMax && ia < NAG) fix_agent(ia, 1);
        }
    }
    // ch region intersection: [F0, F1) ∩ [2*FACN, 2*FACN+CHN)
    else if (t >= 16 && t < 32) {
        long long c0 = max(F0, 2 * FACN), c1 = min(F1, 2 * FACN + CHN);
        if (c0 < c1) {
            int ia = (int)((c0 - 2 * FACN) / SLC) + (t - 16);
            int iaMax = (int)((c1 - 2 * FACN - 1) / SLC);
            if (ia <= iaMax && ia < NAG) fix_agent(ia, 2);
        }
    }
    // safety: block bid writes agent bid (floats past all chunks; exactly one writer)
    else if (t == 40) {
        int ia = bid;
        float px = pos[ia * 2 + 0];
        float py = pos[ia * 2 + 1];
        int x = min(BOARD_ - 1, max(0, (int)px));
        int y = min(BOARD_ - 1, max(0, (int)py));
        int lcell = y * BOARD_ + x;
        bool c;
        if (f == 4)      c = ((const unsigned int*)coll)[ia] != 0u;
        else if (f == 2) c = ((const unsigned short*)coll)[ia] != 0u;
        else             c = ((const unsigned char*)coll)[ia] != 0u;
        float chv = ch_in[(long long)ia * SLC + lcell] * 0.9f + (c ? 0.1f : 0.0f);
        out[2 * FACN + CHN + ia] = 1.0f - fminf(fmaxf(chv, 0.0f), 1.0f);
    }
}

extern "C" void kernel_launch(void* const* d_in, const int* in_sizes, int n_in,
                              void* d_out, int out_size, void* d_ws, size_t ws_size,
                              hipStream_t stream) {
    const float* pos   = (const float*)d_in[0];
    const float* goal  = (const float*)d_in[1];
    const float* spike = (const float*)d_in[2];
    const float* fac   = (const float*)d_in[3];
    const float* inh   = (const float*)d_in[4];
    const float* ch    = (const float*)d_in[5];
    const void*  coll  = d_in[6];
    float* out = (float*)d_out;

    hipLaunchKernelGGL(fused_kernel, dim3(2048), dim3(256), 0, stream,
                       (const f32x4*)fac, (const f32x4*)inh, (const f32x4*)ch, (f32x4*)out,
                       pos, goal, spike, fac, inh, ch, coll, out);
}

// Round 12
// 137.572 us; speedup vs baseline: 1.0922x; 1.0922x over previous
//
#include <hip/hip_runtime.h>

// Problem constants
static constexpr int B_ = 64, A_ = 32, BOARD_ = 64, D_ = 5;
static constexpr long long FACN = (long long)B_ * A_ * BOARD_ * BOARD_ * D_; // 41,943,040 floats
static constexpr long long CHN  = (long long)B_ * A_ * BOARD_ * BOARD_;      //  8,388,608 floats
static constexpr int NAG = B_ * A_;                                          // 2048 agents
static constexpr int SL  = BOARD_ * BOARD_ * D_;                             // 20480 floats / agent fac slab
static constexpr int SLC = BOARD_ * BOARD_;                                  //  4096 floats / agent ch slab

// exp(-1/50), exp(-1/20)
static constexpr float FAC_DECAY = 0.9801986733067553f;
static constexpr float INH_DECAY = 0.9512294245007140f;

typedef float f32x4 __attribute__((ext_vector_type(4)));

// Fused kernel. SINGLE-VARIABLE EXPERIMENT vs r9 (best, 142.5 us):
// 512 blocks x 1024 threads instead of 2048 x 256. Same 524,288 threads and
// same 32-waves/CU occupancy ceiling, but 2 blocks/CU instead of 8 -> 4 long
// sequential DRAM streams per CU instead of 16 interleaved ones.
// Everything else identical: nt loads + nt stores, software pipeline,
// wave-uniform region pick (group = 4096 vectors; FACV and 2*FACV are
// multiples of 4096), chunk-local race-free agent corrections.
__global__ __launch_bounds__(1024) void fused_kernel(
    const f32x4* __restrict__ fac4, const f32x4* __restrict__ inh4,
    const f32x4* __restrict__ ch4, f32x4* __restrict__ out4,
    const float* __restrict__ pos, const float* __restrict__ goal,
    const float* __restrict__ spike,
    const float* __restrict__ fac_in, const float* __restrict__ inh_in,
    const float* __restrict__ ch_in,
    const void* __restrict__ coll,
    float* __restrict__ out)
{
    const int FACV = (int)(FACN / 4);       // 10,485,760 vectors (= 2560*4096)
    const int C = 45056;                    // vectors per block (= 11*4096); 512*C = total
    const int t = threadIdx.x;
    const int bid = blockIdx.x;
    const int base = bid * C;

    __shared__ int s_w4, s_h2;
    if (t == 0) { s_w4 = 1; s_h2 = 1; }
    __syncthreads();

    // ---- Phase 1: streaming decay (groups of 4096 vectors) ----
    auto ldgrp = [&](int G, f32x4 v[4], float& c) {
        const f32x4* __restrict__ s;
        if (G < FACV)          { s = fac4 + G;             c = FAC_DECAY; }
        else if (G < 2 * FACV) { s = inh4 + (G - FACV);    c = INH_DECAY; }
        else                   { s = ch4 + (G - 2 * FACV); c = 0.9f; }
        v[0] = __builtin_nontemporal_load(&s[t]);
        v[1] = __builtin_nontemporal_load(&s[t + 1024]);
        v[2] = __builtin_nontemporal_load(&s[t + 2048]);
        v[3] = __builtin_nontemporal_load(&s[t + 3072]);
    };

    {
        f32x4 v[4]; float c;
        ldgrp(base, v, c);
        int off = 0;
        while (true) {
            f32x4 w[4]; float c2;
            const int noff = off + 4096;
            if (noff < C) ldgrp(base + noff, w, c2);   // prefetch next group first
            f32x4* __restrict__ d = out4 + base + off;
            __builtin_nontemporal_store(v[0] * c, &d[t]);
            __builtin_nontemporal_store(v[1] * c, &d[t + 1024]);
            __builtin_nontemporal_store(v[2] * c, &d[t + 2048]);
            __builtin_nontemporal_store(v[3] * c, &d[t + 3072]);
            if (noff >= C) break;
            v[0] = w[0]; v[1] = w[1]; v[2] = w[2]; v[3] = w[3]; c = c2;
            off = noff;
        }
    }

    // ---- collisions-dtype sniff (2048 bytes = smallest possible encoding) ----
    {
        const unsigned int* cw = (const unsigned int*)coll;
        if (t < 512) {
            unsigned int w = cw[t];
            if (!(w == 0u || w == 1u || w == 0x3F800000u)) s_w4 = 0;
            unsigned int lo = w & 0xFFFFu, hi = w >> 16;
            if (!((lo == 0u || lo == 1u || lo == 0x3F80u || lo == 0x3C00u) &&
                  (hi == 0u || hi == 1u || hi == 0x3F80u || hi == 0x3C00u)))
                s_h2 = 0;
        }
    }
    __threadfence_block();
    __syncthreads();   // this block's streaming stores ordered; sniff flags ready
    const int f = s_w4 ? 4 : (s_h2 ? 2 : 1);

    // ---- Phase 2: chunk-local agent corrections ----
    const long long CF = (long long)C * 4;  // 180,224 floats per chunk
    const long long F0 = (long long)bid * CF, F1 = F0 + CF;

    auto fix_agent = [&](int ia, int region) {  // region 0=fac, 1=inh, 2=ch
        float px = pos[ia * 2 + 0];
        float py = pos[ia * 2 + 1];
        int x = min(BOARD_ - 1, max(0, (int)px));   // trunc like .astype(int32); pos >= 0
        int y = min(BOARD_ - 1, max(0, (int)py));
        int lcell = y * BOARD_ + x;                 // 0..4095

        bool c;
        if (f == 4)      c = ((const unsigned int*)coll)[ia] != 0u;
        else if (f == 2) c = ((const unsigned short*)coll)[ia] != 0u;
        else             c = ((const unsigned char*)coll)[ia] != 0u;

        float chv = ch_in[(long long)ia * SLC + lcell] * 0.9f + (c ? 0.1f : 0.0f);
        float safety = 1.0f - fminf(fmaxf(chv, 0.0f), 1.0f);

        if (region == 2) {
            long long fl = 2 * FACN + (long long)ia * SLC + lcell;
            if (fl >= F0 && fl < F1) out[fl] = chv;
            return;
        }

        bool safe = safety > 0.7f;
        float gx = goal[ia * 2 + 0] - px;
        float gy = goal[ia * 2 + 1] - py;
        float n = sqrtf(gx * gx + gy * gy) + 1e-8f;
        float gnx = gx / n, gny = gy / n;
        float align[5];
        align[0] = 0.5f;
        align[1] = (gnx + 1.0f) * 0.5f;
        align[2] = (gny + 1.0f) * 0.5f;
        align[3] = (1.0f - gnx) * 0.5f;
        align[4] = (1.0f - gny) * 0.5f;

        long long cdb = (long long)ia * SL + (long long)lcell * D_;  // within-region float base
#pragma unroll
        for (int d = 0; d < D_; ++d) {
            bool sp = spike[ia * D_ + d] > 0.5f;
            long long fl;
            float v;
            if (region == 0) {
                bool fc = sp && safe && (align[d] > 0.6f);
                v = fac_in[cdb + d] * FAC_DECAY + (fc ? 0.0002f : 0.0f);
                fl = cdb + d;
            } else {
                bool ic = sp && (!safe || (align[d] <= 0.4f));
                v = inh_in[cdb + d] * INH_DECAY + (ic ? 0.0001f : 0.0f);
                fl = FACN + cdb + d;
            }
            if (fl >= F0 && fl < F1) out[fl] = v;
        }
    };

    // fac region: chunk may touch up to ceil(180224/20480)+1 = 10 slabs -> 16 threads
    if (t < 16) {
        long long a1 = min(F1, FACN);
        if (F0 < a1) {
            int ia = (int)(F0 / SL) + t;
            int iaMax = (int)((a1 - 1) / SL);
            if (ia <= iaMax && ia < NAG) fix_agent(ia, 0);
        }
    }
    // inh region: same bound -> 16 threads
    else if (t < 32) {
        long long b0 = max(F0, FACN), b1 = min(F1, 2 * FACN);
        if (b0 < b1) {
            int ia = (int)((b0 - FACN) / SL) + (t - 16);
            int iaMax = (int)((b1 - FACN - 1) / SL);
            if (ia <= iaMax && ia < NAG) fix_agent(ia, 1);
        }
    }
    // ch region: up to ceil(180224/4096)+1 = 45 slabs -> 48 threads
    else if (t >= 64 && t < 112) {
        long long c0 = max(F0, 2 * FACN), c1 = min(F1, 2 * FACN + CHN);
        if (c0 < c1) {
            int ia = (int)((c0 - 2 * FACN) / SLC) + (t - 64);
            int iaMax = (int)((c1 - 2 * FACN - 1) / SLC);
            if (ia <= iaMax && ia < NAG) fix_agent(ia, 2);
        }
    }
    // safety: 512 blocks x 4 agents = 2048 (floats past all chunks; one writer each)
    else if (t >= 128 && t < 132) {
        int ia = bid * 4 + (t - 128);
        float px = pos[ia * 2 + 0];
        float py = pos[ia * 2 + 1];
        int x = min(BOARD_ - 1, max(0, (int)px));
        int y = min(BOARD_ - 1, max(0, (int)py));
        int lcell = y * BOARD_ + x;
        bool c;
        if (f == 4)      c = ((const unsigned int*)coll)[ia] != 0u;
        else if (f == 2) c = ((const unsigned short*)coll)[ia] != 0u;
        else             c = ((const unsigned char*)coll)[ia] != 0u;
        float chv = ch_in[(long long)ia * SLC + lcell] * 0.9f + (c ? 0.1f : 0.0f);
        out[2 * FACN + CHN + ia] = 1.0f - fminf(fmaxf(chv, 0.0f), 1.0f);
    }
}

extern "C" void kernel_launch(void* const* d_in, const int* in_sizes, int n_in,
                              void* d_out, int out_size, void* d_ws, size_t ws_size,
                              hipStream_t stream) {
    const float* pos   = (const float*)d_in[0];
    const float* goal  = (const float*)d_in[1];
    const float* spike = (const float*)d_in[2];
    const float* fac   = (const float*)d_in[3];
    const float* inh   = (const float*)d_in[4];
    const float* ch    = (const float*)d_in[5];
    const void*  coll  = d_in[6];
    float* out = (float*)d_out;

    hipLaunchKernelGGL(fused_kernel, dim3(512), dim3(1024), 0, stream,
                       (const f32x4*)fac, (const f32x4*)inh, (const f32x4*)ch, (f32x4*)out,
                       pos, goal, spike, fac, inh, ch, coll, out);
}